// Round 12
// baseline (753.751 us; speedup 1.0000x reference)
//
#include <hip/hip_runtime.h>
#include <hip/hip_bf16.h>
#include <hip/hip_cooperative_groups.h>

namespace cg = cooperative_groups;

#define N_NODES 20000
#define N_EDGES 320000
#define HID 256
#define NQ 5000            // nodes per quarter (histogram privatization)
#define NCHUNK 16          // edge chunks per branch
#define ECHUNK (N_EDGES / NCHUNK)   // 20000
#define PREP_BLOCKS 256
#define LAYER_BLOCKS 512

typedef __attribute__((ext_vector_type(8))) short bf16x8;   // MFMA A/B frag
typedef __attribute__((ext_vector_type(4))) float f32x4;    // MFMA C/D frag
typedef __attribute__((ext_vector_type(8))) unsigned short us8;  // 16B row chunk

__device__ __forceinline__ float bf2f(ushort u) {
  union { unsigned int i; float f; } v; v.i = ((unsigned int)u) << 16; return v.f;
}
__device__ __forceinline__ ushort f2bf(float f) {
  union { float f; unsigned int i; } v; v.f = f;
  unsigned int r = v.i + 0x7FFFu + ((v.i >> 16) & 1u);   // RNE
  return (ushort)(r >> 16);
}

// ===========================================================================
// prep_kernel (cooperative, 256 blocks x 1024 thr):
//   P0  zero cnt/t; block 255 detects dtypes (flags[0]=x fp32, flags[1]=ei64)
//   P1  count blocks (bx<128 = 16 chunks x 4 quarters x 2 branches): LDS
//       histogram over own edge chunk, COALESCED atomic merge -> cnt,
//       capturing per-node base in LDS (persists across grid.sync since the
//       block stays resident). t blocks (bx>=128): zero LDS t-accumulator.
//   P2  blocks 128/129: exclusive scan cnt -> rp, fused dinv=rsqrt(cnt+1).
//   P3  count blocks: second pass -> slot = rp[dst]+base+LDS-rank, write eg
//       packed 4B (low16=src, high16=bf16(coef)) -- NO global rank array.
//       t blocks: LDS-privatized t[src]+=dinv[dst], coalesced merge.
// Replaces 4 kernels + 3 launch boundaries (r11 budget: ~160us of gaps).
// ===========================================================================
__global__ __launch_bounds__(1024) void prep_kernel(
    const void* e0, const void* e1, const void* x1,
    int* cnt0, int* cnt1, int* rp0, int* rp1,
    float* dinv0, float* dinv1,
    unsigned int* eg0, unsigned int* eg1,
    float* t0, float* t1, int* flags) {
  cg::grid_group grid = cg::this_grid();
  __shared__ int hist[NQ];     // count: histogram/rank ctr | t-roles: float accum
  __shared__ int base[NQ];
  __shared__ int sd[1024];     // scan workspace (blocks 128/129)
  __shared__ int dw, dz;
  int bx = blockIdx.x, tid = threadIdx.x;

  // ---- P0: zero + detect ----
  int idx = bx * 1024 + tid;
  if (idx < N_NODES) { cnt0[idx] = 0; cnt1[idx] = 0; t0[idx] = 0.f; t1[idx] = 0.f; }
  if (bx == PREP_BLOCKS - 1) {
    if (tid == 0) { dw = 0; dz = 0; }
    __syncthreads();
    if (tid < 256) {
      const ushort* xu = (const ushort*)x1;
      int wild = 0;
#pragma unroll
      for (int k = 0; k < 4; k++) {
        ushort u = xu[tid * 4 + k];
        int ex = (u >> 7) & 0xFF;
        if (ex >= 0x90) wild++;
      }
      if (wild) atomicAdd(&dw, wild);
      if (((const int*)e0)[tid * 2 + 1] != 0) atomicAdd(&dz, 1);
    }
    __syncthreads();
    if (tid == 0) { flags[0] = (dw > 64) ? 1 : 0; flags[1] = (dz < 8) ? 1 : 0; }
  }
  grid.sync();

  bool w64 = flags[1] != 0;
  int role = (bx < 128) ? bx : bx - 128;
  int branch = role & 1;
  int lo = ((role >> 1) & 3) * NQ;
  int ebeg = (role >> 3) * ECHUNK;
  const void* e = branch ? e1 : e0;
  const int* s32 = (const int*)e;
  const int* d32 = (const int*)e + N_EDGES;
  const long long* s64 = (const long long*)e;
  const long long* d64 = (const long long*)e + N_EDGES;

  // ---- P1 ----
  if (bx < 128) {
    for (int k = tid; k < NQ; k += 1024) hist[k] = 0;
    __syncthreads();
    for (int i = ebeg + tid; i < ebeg + ECHUNK; i += 1024) {
      int d = w64 ? (int)d64[i] : d32[i];
      unsigned q = (unsigned)(d - lo);
      if (q < NQ) atomicAdd(&hist[q], 1);
    }
    __syncthreads();
    int* cnt = branch ? cnt1 : cnt0;
    for (int k = tid; k < NQ; k += 1024) {
      base[k] = atomicAdd(&cnt[lo + k], hist[k]);   // coalesced merge
      hist[k] = 0;                                  // reuse as local rank ctr
    }
  } else {
    float* tl = (float*)hist;
    for (int k = tid; k < NQ; k += 1024) tl[k] = 0.f;
  }
  grid.sync();

  // ---- P2: scan + dinv (blocks 128, 129) ----
  if (bx == 128 || bx == 129) {
    int b = bx - 128;
    const int* cnt = b ? cnt1 : cnt0;
    int* rp = b ? rp1 : rp0;
    float* dinv = b ? dinv1 : dinv0;
    int bb = tid * 20;
    int pref[20];
    int run = 0;
#pragma unroll
    for (int k = 0; k < 20; k++) {
      int i = bb + k;
      int c = (i < N_NODES) ? cnt[i] : 0;
      if (i < N_NODES) dinv[i] = rsqrtf((float)c + 1.0f);
      run += c;
      pref[k] = run;
    }
    sd[tid] = run;
    __syncthreads();
    for (int off = 1; off < 1024; off <<= 1) {
      int v = (tid >= off) ? sd[tid - off] : 0;
      __syncthreads();
      sd[tid] += v;
      __syncthreads();
    }
    int offset = sd[tid] - run;
    if (tid == 0) rp[0] = 0;
#pragma unroll
    for (int k = 0; k < 20; k++) {
      int i = bb + k;
      if (i < N_NODES) rp[i + 1] = offset + pref[k];
    }
  }
  grid.sync();

  // ---- P3 ----
  const float* dinv = branch ? dinv1 : dinv0;
  if (bx < 128) {
    const int* rp = branch ? rp1 : rp0;
    unsigned int* eg = branch ? eg1 : eg0;
    for (int i = ebeg + tid; i < ebeg + ECHUNK; i += 1024) {
      int d = w64 ? (int)d64[i] : d32[i];
      unsigned q = (unsigned)(d - lo);
      if (q < NQ) {
        int s = w64 ? (int)s64[i] : s32[i];
        int r = atomicAdd(&hist[q], 1);
        int slot = rp[d] + base[q] + r;
        eg[slot] = (unsigned int)s | ((unsigned int)f2bf(dinv[s] * dinv[d]) << 16);
      }
    }
  } else {
    float* tl = (float*)hist;
    float* t = branch ? t1 : t0;
    for (int i = ebeg + tid; i < ebeg + ECHUNK; i += 1024) {
      int s = w64 ? (int)s64[i] : s32[i];
      unsigned q = (unsigned)(s - lo);
      if (q < NQ) {
        int d = w64 ? (int)d64[i] : d32[i];
        atomicAdd(&tl[q], dinv[d]);
      }
    }
    __syncthreads();
    for (int k = tid; k < NQ; k += 1024)
      atomicAdd(&t[lo + k], tl[k]);                 // coalesced merge
  }
}

// ===========================================================================
// layer_kernel (cooperative, 512 blocks x 256 thr):
//   P0 gemm (157x4x2 tile roles, grid-strided): C = A @ W, 128x64 tile,
//      raw A (fp32/bf16 uniform branch when maybe_f32) and raw W
//      (coalesced read + stride-42 LDS transpose).
//   grid.sync
//   P1 agg (5000 roles): H[i] = relu(dinv_i^2*XW[i] + sum coef*XW[src] + b);
//      wave = 2 independent halves, 8 full rows in flight (r8/r9 lesson).
//   if last: grid.sync; P2 colsum partials; grid.sync; P3 final on block 0.
// ===========================================================================
__global__ __launch_bounds__(256) void layer_kernel(
    const void* A0, const void* A1, const void* W,
    ushort* C0, ushort* C1,
    const void* bias,
    ushort* H0, ushort* H1,
    const float* dinv0, const float* dinv1,
    const int* rp0, const int* rp1,
    const unsigned int* eg0, const unsigned int* eg1,
    const float* t0, const float* t1,
    float* P,
    const void* W3, const void* b3, const void* Wl, const void* bl,
    void* out, const int* flags, int maybe_f32, int last) {
  cg::grid_group grid = cg::this_grid();
  __shared__ ushort As[128][42];
  __shared__ ushort Bs[64][42];
  __shared__ float part[4][256];
  __shared__ float vv[256];
  __shared__ float pooled[256];
  int tid = threadIdx.x;
  int wave = tid >> 6, lane = tid & 63;
  int quad = lane >> 4, r16 = lane & 15;
  bool wf32 = flags[0] != 0;
  bool af32 = maybe_f32 && wf32;

  // ---- P0: gemm tile roles ----
  for (int role = blockIdx.x; role < 157 * 4 * 2; role += LAYER_BLOCKS) {
    int z = role & 1;
    int n0 = ((role >> 1) & 3) * 64;
    int m0 = (role >> 3) * 128;
    const void* A = z ? A1 : A0;
    ushort* C = z ? C1 : C0;
    f32x4 acc[2][4];
#pragma unroll
    for (int m = 0; m < 2; m++)
#pragma unroll
      for (int n = 0; n < 4; n++) acc[m][n] = (f32x4){0.f, 0.f, 0.f, 0.f};
    int la_row = tid >> 1;
    int la_c0 = (tid & 1) * 16;
    int bk = tid >> 3;
    int bn0 = (tid & 7) * 8;
    for (int k0 = 0; k0 < 256; k0 += 32) {
      int gr = m0 + la_row;
      if (af32) {
        const float* Af = (const float*)A;
        float4 v0 = {0,0,0,0}, v1 = v0, v2 = v0, v3 = v0;
        if (gr < N_NODES) {
          const float* pA = Af + gr * 256 + k0 + la_c0;
          v0 = *(const float4*)pA;       v1 = *(const float4*)(pA + 4);
          v2 = *(const float4*)(pA + 8); v3 = *(const float4*)(pA + 12);
        }
        ushort* d = &As[la_row][la_c0];
        d[0] = f2bf(v0.x); d[1] = f2bf(v0.y); d[2]  = f2bf(v0.z); d[3]  = f2bf(v0.w);
        d[4] = f2bf(v1.x); d[5] = f2bf(v1.y); d[6]  = f2bf(v1.z); d[7]  = f2bf(v1.w);
        d[8] = f2bf(v2.x); d[9] = f2bf(v2.y); d[10] = f2bf(v2.z); d[11] = f2bf(v2.w);
        d[12] = f2bf(v3.x); d[13] = f2bf(v3.y); d[14] = f2bf(v3.z); d[15] = f2bf(v3.w);
      } else {
        const ushort* Ab = (const ushort*)A;
        int4 w0 = {0,0,0,0}, w1 = w0;
        if (gr < N_NODES) {
          const ushort* pA = Ab + gr * 256 + k0 + la_c0;
          w0 = *(const int4*)pA;
          w1 = *(const int4*)(pA + 8);
        }
        *(int4*)&As[la_row][la_c0] = w0;
        *(int4*)&As[la_row][la_c0 + 8] = w1;
      }
      ushort wtmp[8];
      if (wf32) {
        const float* Wf = (const float*)W + (k0 + bk) * 256 + n0 + bn0;
        float4 u0 = *(const float4*)Wf;
        float4 u1 = *(const float4*)(Wf + 4);
        wtmp[0] = f2bf(u0.x); wtmp[1] = f2bf(u0.y); wtmp[2] = f2bf(u0.z); wtmp[3] = f2bf(u0.w);
        wtmp[4] = f2bf(u1.x); wtmp[5] = f2bf(u1.y); wtmp[6] = f2bf(u1.z); wtmp[7] = f2bf(u1.w);
      } else {
        *(int4*)wtmp = *(const int4*)((const ushort*)W + (k0 + bk) * 256 + n0 + bn0);
      }
#pragma unroll
      for (int j = 0; j < 8; j++) Bs[bn0 + j][bk] = wtmp[j];   // transpose scatter
      __syncthreads();
      bf16x8 a0 = *(const bf16x8*)&As[wave * 32 + r16][quad * 8];
      bf16x8 a1 = *(const bf16x8*)&As[wave * 32 + 16 + r16][quad * 8];
      bf16x8 bb0 = *(const bf16x8*)&Bs[r16][quad * 8];
      bf16x8 bb1 = *(const bf16x8*)&Bs[16 + r16][quad * 8];
      bf16x8 bb2 = *(const bf16x8*)&Bs[32 + r16][quad * 8];
      bf16x8 bb3 = *(const bf16x8*)&Bs[48 + r16][quad * 8];
      acc[0][0] = __builtin_amdgcn_mfma_f32_16x16x32_bf16(a0, bb0, acc[0][0], 0, 0, 0);
      acc[0][1] = __builtin_amdgcn_mfma_f32_16x16x32_bf16(a0, bb1, acc[0][1], 0, 0, 0);
      acc[0][2] = __builtin_amdgcn_mfma_f32_16x16x32_bf16(a0, bb2, acc[0][2], 0, 0, 0);
      acc[0][3] = __builtin_amdgcn_mfma_f32_16x16x32_bf16(a0, bb3, acc[0][3], 0, 0, 0);
      acc[1][0] = __builtin_amdgcn_mfma_f32_16x16x32_bf16(a1, bb0, acc[1][0], 0, 0, 0);
      acc[1][1] = __builtin_amdgcn_mfma_f32_16x16x32_bf16(a1, bb1, acc[1][1], 0, 0, 0);
      acc[1][2] = __builtin_amdgcn_mfma_f32_16x16x32_bf16(a1, bb2, acc[1][2], 0, 0, 0);
      acc[1][3] = __builtin_amdgcn_mfma_f32_16x16x32_bf16(a1, bb3, acc[1][3], 0, 0, 0);
      __syncthreads();
    }
#pragma unroll
    for (int m = 0; m < 2; m++) {
      int grb = m0 + wave * 32 + m * 16 + quad * 4;
#pragma unroll
      for (int r = 0; r < 4; r++) {
        int gr = grb + r;
        if (gr < N_NODES) {
          ushort* cp = C + gr * 256 + n0 + r16;
          cp[0]  = f2bf(acc[m][0][r]);
          cp[16] = f2bf(acc[m][1][r]);
          cp[32] = f2bf(acc[m][2][r]);
          cp[48] = f2bf(acc[m][3][r]);
        }
      }
    }
  }
  grid.sync();

  // ---- P1: agg roles ----
  {
    int half = lane >> 5;
    int fl = (lane & 31) * 8;
    for (int role = blockIdx.x; role < 5000; role += LAYER_BLOCKS) {
      int b = role & 1;
      int nb = role >> 1;
      const ushort* XW = b ? C1 : C0;
      const float* dinv = b ? dinv1 : dinv0;
      const int* rp = b ? rp1 : rp0;
      const unsigned int* eg = b ? eg1 : eg0;
      ushort* H = b ? H1 : H0;
      int i = nb * 8 + wave * 2 + half;   // 2500*8 = 20000 exact
      float di = dinv[i];
      float selfw = di * di;
      us8 v = *(const us8*)(XW + i * 256 + fl);
      float acc[8], acc2[8];
#pragma unroll
      for (int k = 0; k < 8; k++) { acc[k] = selfw * bf2f(v[k]); acc2[k] = 0.f; }
      int e = rp[i], eend = rp[i + 1];
      for (; e + 4 <= eend; e += 4) {
        unsigned int p0 = eg[e], p1 = eg[e + 1], p2 = eg[e + 2], p3 = eg[e + 3];
        us8 r0 = *(const us8*)(XW + (p0 & 0xFFFFu) * 256 + fl);
        us8 r1 = *(const us8*)(XW + (p1 & 0xFFFFu) * 256 + fl);
        us8 r2 = *(const us8*)(XW + (p2 & 0xFFFFu) * 256 + fl);
        us8 r3 = *(const us8*)(XW + (p3 & 0xFFFFu) * 256 + fl);
        float w0 = bf2f((ushort)(p0 >> 16)), w1 = bf2f((ushort)(p1 >> 16));
        float w2 = bf2f((ushort)(p2 >> 16)), w3 = bf2f((ushort)(p3 >> 16));
#pragma unroll
        for (int k = 0; k < 8; k++) {
          acc[k]  += w0 * bf2f(r0[k]);
          acc2[k] += w1 * bf2f(r1[k]);
          acc[k]  += w2 * bf2f(r2[k]);
          acc2[k] += w3 * bf2f(r3[k]);
        }
      }
      for (; e < eend; e++) {
        unsigned int pp = eg[e];
        us8 r = *(const us8*)(XW + (pp & 0xFFFFu) * 256 + fl);
        float w = bf2f((ushort)(pp >> 16));
#pragma unroll
        for (int k = 0; k < 8; k++) acc[k] += w * bf2f(r[k]);
      }
      float bv[8];
      if (wf32) {
        const float* bf = (const float*)bias + fl;
        float4 c0 = *(const float4*)bf;
        float4 c1 = *(const float4*)(bf + 4);
        bv[0] = c0.x; bv[1] = c0.y; bv[2] = c0.z; bv[3] = c0.w;
        bv[4] = c1.x; bv[5] = c1.y; bv[6] = c1.z; bv[7] = c1.w;
      } else {
        us8 bb = *(const us8*)((const ushort*)bias + fl);
#pragma unroll
        for (int k = 0; k < 8; k++) bv[k] = bf2f(bb[k]);
      }
      us8 o;
#pragma unroll
      for (int k = 0; k < 8; k++)
        o[k] = f2bf(fmaxf(acc[k] + acc2[k] + bv[k], 0.f));
      *(us8*)(H + i * 256 + fl) = o;
    }
  }

  if (!last) return;
  grid.sync();

  // ---- P2: colsum partials (128 roles) ----
  for (int role = blockIdx.x; role < 128; role += LAYER_BLOCKS) {
    int b = role & 1;
    int cx = role >> 1;
    const ushort* H = b ? H1 : H0;
    const float* dinv = b ? dinv1 : dinv0;
    const float* t = b ? t1 : t0;
    int wid = cx * 4 + wave;
    int f4 = lane * 4;
    float a0 = 0.f, a1 = 0.f, a2 = 0.f, a3 = 0.f;
    for (int j = wid; j < N_NODES; j += 256) {
      float dj = dinv[j];
      float c = dj * (t[j] + dj);
      ushort4 u = *(const ushort4*)(H + j * 256 + f4);
      a0 += c * bf2f(u.x); a1 += c * bf2f(u.y);
      a2 += c * bf2f(u.z); a3 += c * bf2f(u.w);
    }
    part[wave][f4 + 0] = a0; part[wave][f4 + 1] = a1;
    part[wave][f4 + 2] = a2; part[wave][f4 + 3] = a3;
    __syncthreads();
    int f = tid;
    float ssum = part[0][f] + part[1][f] + part[2][f] + part[3][f];
    P[(b * 64 + cx) * 256 + f] = ssum;
    __syncthreads();
  }
  grid.sync();

  // ---- P3: final (block 0) ----
  if (blockIdx.x == 0) {
    int t = tid;
    float acc0 = 0.f, acc1 = 0.f;
    for (int b = 0; b < 64; b++) {
      acc0 += P[b * 256 + t];
      acc1 += P[(64 + b) * 256 + t];
    }
    vv[t] = acc0 + acc1;
    __syncthreads();
    float acc = 0.f;
    if (wf32) {
      const float* W3f = (const float*)W3;
      for (int f = 0; f < 256; f++) acc += vv[f] * W3f[f * 256 + t];
      pooled[t] = acc * (1.0f / (2.0f * N_NODES)) + ((const float*)b3)[t];
    } else {
      const ushort* W3b = (const ushort*)W3;
      for (int f = 0; f < 256; f++) acc += vv[f] * bf2f(W3b[f * 256 + t]);
      pooled[t] = acc * (1.0f / (2.0f * N_NODES)) + bf2f(((const ushort*)b3)[t]);
    }
    __syncthreads();
    if (t < 5) {
      float o;
      if (wf32) {
        o = ((const float*)bl)[t];
        for (int h = 0; h < 256; h++) o += pooled[h] * ((const float*)Wl)[h * 5 + t];
        ((float*)out)[t] = o;
      } else {
        o = bf2f(((const ushort*)bl)[t]);
        for (int h = 0; h < 256; h++) o += pooled[h] * bf2f(((const ushort*)Wl)[h * 5 + t]);
        ((ushort*)out)[t] = f2bf(o);
      }
    }
  }
}

extern "C" void kernel_launch(void* const* d_in, const int* in_sizes, int n_in,
                              void* d_out, int out_size, void* d_ws, size_t ws_size,
                              hipStream_t stream) {
  const void* x1 = d_in[0];
  const void* ei1 = d_in[1];
  const void* x2 = d_in[2];
  const void* ei2 = d_in[3];
  const void* W1 = d_in[4];
  const void* b1 = d_in[5];
  const void* W2 = d_in[6];
  const void* b2 = d_in[7];
  const void* W3 = d_in[8];
  const void* b3 = d_in[9];
  const void* Wl = d_in[10];
  const void* bl = d_in[11];
  void* out = d_out;

  char* p = (char*)d_ws;
  auto alloc = [&](size_t bytes) {
    char* r = p;
    p += (bytes + 255) & ~size_t(255);
    return r;
  };
  int* flags   = (int*)alloc(256);
  float* dinv0 = (float*)alloc(N_NODES * 4);
  float* dinv1 = (float*)alloc(N_NODES * 4);
  float* t0    = (float*)alloc(N_NODES * 4);
  float* t1    = (float*)alloc(N_NODES * 4);
  int* cnt0    = (int*)alloc(N_NODES * 4);
  int* cnt1    = (int*)alloc(N_NODES * 4);
  int* rp0     = (int*)alloc((N_NODES + 1) * 4);
  int* rp1     = (int*)alloc((N_NODES + 1) * 4);
  unsigned int* eg0 = (unsigned int*)alloc((size_t)N_EDGES * 4);
  unsigned int* eg1 = (unsigned int*)alloc((size_t)N_EDGES * 4);
  float* Pp    = (float*)alloc(2 * 64 * 256 * 4);
  ushort* xw0  = (ushort*)alloc((size_t)N_NODES * HID * 2);
  ushort* xw1  = (ushort*)alloc((size_t)N_NODES * HID * 2);
  ushort* h0   = (ushort*)alloc((size_t)N_NODES * HID * 2);
  ushort* h1   = (ushort*)alloc((size_t)N_NODES * HID * 2);

  // --- prep: init+detect, count+rank, scan+dinv, eg-scatter + t (1 launch) ---
  {
    void* args[] = {(void*)&ei1, (void*)&ei2, (void*)&x1,
                    &cnt0, &cnt1, &rp0, &rp1, &dinv0, &dinv1,
                    &eg0, &eg1, &t0, &t1, &flags};
    hipLaunchCooperativeKernel((const void*)prep_kernel, dim3(PREP_BLOCKS),
                               dim3(1024), args, 0, stream);
  }
  int one = 1, zero = 0;
  // --- layer 1: gemm(x@W1) + agg -> h ---
  {
    void* args[] = {(void*)&x1, (void*)&x2, (void*)&W1, &xw0, &xw1,
                    (void*)&b1, &h0, &h1, &dinv0, &dinv1, &rp0, &rp1,
                    &eg0, &eg1, &t0, &t1, &Pp,
                    (void*)&W3, (void*)&b3, (void*)&Wl, (void*)&bl,
                    &out, &flags, &one, &zero};
    hipLaunchCooperativeKernel((const void*)layer_kernel, dim3(LAYER_BLOCKS),
                               dim3(256), args, 0, stream);
  }
  // --- layer 2: gemm(h@W2) + agg + colsum + final ---
  {
    void* h0c = h0, *h1c = h1;
    void* args[] = {&h0c, &h1c, (void*)&W2, &xw0, &xw1,
                    (void*)&b2, &h0, &h1, &dinv0, &dinv1, &rp0, &rp1,
                    &eg0, &eg1, &t0, &t1, &Pp,
                    (void*)&W3, (void*)&b3, (void*)&Wl, (void*)&bl,
                    &out, &flags, &zero, &one};
    hipLaunchCooperativeKernel((const void*)layer_kernel, dim3(LAYER_BLOCKS),
                               dim3(256), args, 0, stream);
  }
}